// Round 1
// 905.228 us; speedup vs baseline: 1.3116x; 1.3116x over previous
//
#include <hip/hip_runtime.h>
#include <hip/hip_bf16.h>

typedef __bf16 bf16_t;
typedef __bf16 bf16x8 __attribute__((ext_vector_type(8)));
typedef __bf16 bf16x4 __attribute__((ext_vector_type(4)));
typedef __bf16 bf16x2 __attribute__((ext_vector_type(2)));
typedef float f32x4 __attribute__((ext_vector_type(4)));

constexpr int Hh = 56;
constexpr int Ww = 56;
constexpr int Cc = 512;
constexpr int NHd = 16;
constexpr int HD = 32;
constexpr int SSh = 3;
constexpr int Nn = 49;          // tokens per window
constexpr long Mtot = 100352;   // 32*64*49 windowed tokens
#define SCALE 0.17677669529663687f

// token (windowed order) -> pixel index in x / out. Identical map for gather and scatter.
__device__ __forceinline__ int token_to_pixel(int m) {
  int bw = m / Nn;
  int n  = m - bw * Nn;
  int b  = bw >> 6;
  int w6 = bw & 63;
  int wh = w6 >> 3, ww = w6 & 7;
  int r = n / 7, c = n - r * 7;
  int hh = wh * 7 + r + SSh; if (hh >= Hh) hh -= Hh;
  int wp = ww * 7 + c + SSh; if (wp >= Ww) wp -= Ww;
  return (b * Hh + hh) * Ww + wp;
}

// C[m][n] = sum_k A[m][k]*W[n][k] (+bias).
// MODE 0: A = x (f32, rows gathered via shifted-window map), W = qkv_w (f32);
//         scatter bf16 q/k/v into (bw,h,n,d) layout; q pre-scaled by SCALE.
// MODE 1: A = attn_out in (bw,h,n,d) layout (bf16), W = proj_w (f32);
//         scatter f32 output to rolled pixel layout.
template <int MODE>
__global__ __launch_bounds__(256, 2)
void gemm_k(const void* __restrict__ Asrc_, const float* __restrict__ Wt,
            const float* __restrict__ bias,
            bf16_t* __restrict__ oq, bf16_t* __restrict__ okk, bf16_t* __restrict__ ov,
            float* __restrict__ of) {
  __shared__ __align__(16) bf16_t lA[128 * 32];
  __shared__ __align__(16) bf16_t lB[128 * 32];
  const int t = threadIdx.x;
  const int mtile = blockIdx.x, ntile = blockIdx.y;
  const int lane = t & 63;
  const int wave = t >> 6;
  const int wr = wave >> 1, wc = wave & 1;
  const int quad = lane >> 4, l15 = lane & 15;

  // staging: thread t covers row0 (+64), cols part*8..part*8+8 of the k-slab
  const int row0 = t >> 2, part = t & 3;
  const float* aPtrF[2];
  const bf16_t* aPtrB[2];
  const float* bPtrF[2];
#pragma unroll
  for (int u = 0; u < 2; ++u) {
    int rA = row0 + u * 64;
    int m = mtile * 128 + rA;
    if (MODE == 0) {
      aPtrF[u] = (const float*)Asrc_ + (long)token_to_pixel(m) * Cc + part * 8;
    } else {
      int bw2 = m / Nn, nn = m - bw2 * Nn;
      aPtrB[u] = (const bf16_t*)Asrc_ + (long)bw2 * (Nn * Cc) + nn * HD + part * 8;
    }
    int nIdx = ntile * 128 + rA;
    bPtrF[u] = Wt + (long)nIdx * Cc + part * 8;
  }

  f32x4 acc[4][4] = {};

  for (int k0 = 0; k0 < Cc; k0 += 32) {
    // global -> registers (f32), convert -> bf16
    bf16x8 aReg[2], bReg[2];
#pragma unroll
    for (int u = 0; u < 2; ++u) {
      if (MODE == 0) {
        f32x4 a0 = *(const f32x4*)(aPtrF[u] + k0);
        f32x4 a1 = *(const f32x4*)(aPtrF[u] + k0 + 4);
#pragma unroll
        for (int e = 0; e < 4; ++e) { aReg[u][e] = (bf16_t)a0[e]; aReg[u][e + 4] = (bf16_t)a1[e]; }
      } else {
        // k = h*32 + d; (bw,h,n,d) layout => step 49*32 elements per 32-k slab
        aReg[u] = *(const bf16x8*)(aPtrB[u] + k0 * Nn);
      }
      f32x4 b0 = *(const f32x4*)(bPtrF[u] + k0);
      f32x4 b1 = *(const f32x4*)(bPtrF[u] + k0 + 4);
#pragma unroll
      for (int e = 0; e < 4; ++e) { bReg[u][e] = (bf16_t)b0[e]; bReg[u][e + 4] = (bf16_t)b1[e]; }
    }
    __syncthreads();   // previous iteration's fragment reads complete
    *(bf16x8*)(lA + t * 8)        = aReg[0];
    *(bf16x8*)(lA + t * 8 + 2048) = aReg[1];
    *(bf16x8*)(lB + t * 8)        = bReg[0];
    *(bf16x8*)(lB + t * 8 + 2048) = bReg[1];
    __syncthreads();   // stores visible

    bf16x8 af[4], bfr[4];
#pragma unroll
    for (int i = 0; i < 4; ++i)
      af[i] = *(const bf16x8*)(lA + (wr * 64 + i * 16 + l15) * 32 + quad * 8);
#pragma unroll
    for (int j = 0; j < 4; ++j)
      bfr[j] = *(const bf16x8*)(lB + (wc * 64 + j * 16 + l15) * 32 + quad * 8);
#pragma unroll
    for (int i = 0; i < 4; ++i)
#pragma unroll
      for (int j = 0; j < 4; ++j)
        acc[i][j] = __builtin_amdgcn_mfma_f32_16x16x32_bf16(af[i], bfr[j], acc[i][j], 0, 0, 0);
  }

#pragma unroll
  for (int i = 0; i < 4; ++i) {
#pragma unroll
    for (int rg = 0; rg < 4; ++rg) {
      int m = mtile * 128 + wr * 64 + i * 16 + quad * 4 + rg;
      if (MODE == 0) {
        int bw = m / Nn, n = m - bw * Nn;
#pragma unroll
        for (int j = 0; j < 4; ++j) {
          int jg = ntile * 128 + wc * 64 + j * 16 + l15;
          float v = acc[i][j][rg] + bias[jg];
          int which = jg >> 9;
          if (which == 0) v *= SCALE;   // fold softmax scale into q
          int h = (jg >> 5) & 15;
          int d = jg & 31;
          long idx = (((long)bw * NHd + h) * Nn + n) * HD + d;
          bf16_t* dst = (which == 0) ? oq : ((which == 1) ? okk : ov);
          dst[idx] = (bf16_t)v;
        }
      } else {
        long pb = (long)token_to_pixel(m) * Cc;
#pragma unroll
        for (int j = 0; j < 4; ++j) {
          int jg = ntile * 128 + wc * 64 + j * 16 + l15;
          of[pb + jg] = acc[i][j][rg] + bias[jg];
        }
      }
    }
  }
}

// Precompute bm[class][h][n][m] = rel-pos bias + shift mask, bf16, [64][64] padded
// with -1e30 for n>=49 or m>=49 (=> exp -> 0, so MFMA padding lanes self-mask).
// class = 2*(wh==7) + (ww==7).
__global__ void bm_fill(const float* __restrict__ table, bf16_t* __restrict__ bm) {
  const int b = blockIdx.x;           // cls*16 + h
  const int cls = b >> 4, h = b & 15;
  const int whE = cls >> 1, wwE = cls & 1;
  for (int e = threadIdx.x; e < 4096; e += 256) {
    int n = e >> 6, m = e & 63;
    float v = -1e30f;
    if (n < Nn && m < Nn) {
      int r1 = n / 7, c1 = n - r1 * 7;
      int r2 = m / 7, c2 = m - r2 * 7;
      int idx = (r1 - r2 + 6) * 13 + (c1 - c2 + 6);
      v = table[idx * NHd + h];
      int reg1 = (whE ? ((r1 < 4) ? 1 : 2) : 0) * 3 + (wwE ? ((c1 < 4) ? 1 : 2) : 0);
      int reg2 = (whE ? ((r2 < 4) ? 1 : 2) : 0) * 3 + (wwE ? ((c2 < 4) ? 1 : 2) : 0);
      if (reg1 != reg2) v -= 100.f;
    }
    bm[(long)b * 4096 + e] = (bf16_t)v;
  }
}

// MFMA attention. One block per window, 4 waves x 4 heads, no __syncthreads
// (all LDS buffers are per-wave). Per head:
//   S^T = K . Qs^T    (16 mfma, swapped so P is m-contiguous per lane)
//   softmax in-reg    (bm fused bias+mask+pad; 2 shfl_xor row-sum; P -> LDS bf16)
//   O^T = VT . P^T    (16 mfma; output d-contiguous per lane)
// Output overwrites the q region (read-before-write within the wave), layout (bw,h,n,d).
__global__ __launch_bounds__(256, 2)
void attn_k(bf16_t* __restrict__ qr, const bf16_t* __restrict__ kr,
            const bf16_t* __restrict__ vr, const bf16_t* __restrict__ bm) {
  __shared__ __align__(16) bf16_t vt[4][32 * 72];   // V^T per wave: [d][m], stride 72
  __shared__ __align__(16) bf16_t pbuf[4][64 * 72]; // P per wave: [n][m], stride 72
  const int t = threadIdx.x, wave = t >> 6, lane = t & 63;
  const int quad = lane >> 4, l15 = lane & 15;
  const int bw = blockIdx.x;
  const int w6 = bw & 63, wh = w6 >> 3, ww = w6 & 7;
  const int cls = ((wh == 7) ? 2 : 0) | ((ww == 7) ? 1 : 0);
  bf16_t* vtw = vt[wave];
  bf16_t* pw  = pbuf[wave];

  // zero vt once: cols 50..63 stay zero forever (m-padding for PV), avoids NaN garbage
  {
    bf16x8 z = {};
    for (int c = lane; c < 288; c += 64) *(bf16x8*)(vtw + c * 8) = z;
  }

  const int dc = lane & 3;        // d-chunk of 8 for V transpose staging
  const int mp = lane >> 2;       // m-pair index
  const int m2 = 32 + 2 * mp;
  const int ma = (m2 > 48) ? 48 : m2;
  const int mb = (m2 + 1 > 48) ? 48 : m2 + 1;

#pragma unroll 1
  for (int hi = 0; hi < 4; ++hi) {
    const int h = wave * 4 + hi;
    const long base = (long)(bw * NHd + h) * (Nn * HD);
    const bf16_t* K = kr + base;
    const bf16_t* Q = qr + base;
    const bf16_t* V = vr + base;

    // K/Q fragments straight from global: 16 consecutive rows x 64B = coalesced 1KB/instr.
    // Rows 49..63 over-read into the next head slab: finite garbage, masked by bm pad.
    bf16x8 kf[4], qf[4];
#pragma unroll
    for (int i = 0; i < 4; ++i) {
      kf[i] = *(const bf16x8*)(K + (i * 16 + l15) * HD + quad * 8);
      qf[i] = *(const bf16x8*)(Q + (i * 16 + l15) * HD + quad * 8);
    }
    // V staging loads (issued early; LDS transpose-writes happen after the MFMAs)
    bf16x8 v0a = *(const bf16x8*)(V + (2 * mp) * HD + dc * 8);
    bf16x8 v0b = *(const bf16x8*)(V + (2 * mp + 1) * HD + dc * 8);
    bf16x8 v1a = *(const bf16x8*)(V + ma * HD + dc * 8);
    bf16x8 v1b = *(const bf16x8*)(V + mb * HD + dc * 8);

    // S^T[m][n] = sum_d K[m][d] * Qs[n][d]
    f32x4 acc[4][4];
#pragma unroll
    for (int i = 0; i < 4; ++i)
#pragma unroll
      for (int j = 0; j < 4; ++j) {
        f32x4 z = {};
        acc[i][j] = z;
      }
#pragma unroll
    for (int i = 0; i < 4; ++i)
#pragma unroll
      for (int j = 0; j < 4; ++j)
        acc[i][j] = __builtin_amdgcn_mfma_f32_16x16x32_bf16(kf[i], qf[j], acc[i][j], 0, 0, 0);

    // V^T into LDS: vt[d][m], packed bf16x2 writes (pairs of m)
#pragma unroll
    for (int e = 0; e < 8; ++e) {
      int d = dc * 8 + e;
      bf16x2 w0; w0[0] = v0a[e]; w0[1] = v0b[e];
      *(bf16x2*)(vtw + d * 72 + 2 * mp) = w0;
      if (mp <= 8) {
        bf16x2 w1; w1[0] = v1a[e]; w1[1] = (mp < 8) ? v1b[e] : (bf16_t)0.0f;
        *(bf16x2*)(vtw + d * 72 + ma) = w1;
      }
    }

    // bias+mask+pad, exp, row-sum, normalized P -> LDS
    const bf16_t* bmh = bm + ((long)(cls * NHd + h) << 12);
    float psum[4] = {0.f, 0.f, 0.f, 0.f};
#pragma unroll
    for (int j = 0; j < 4; ++j) {
      const int n = j * 16 + l15;
#pragma unroll
      for (int i = 0; i < 4; ++i) {
        bf16x4 bmv = *(const bf16x4*)(bmh + n * 64 + i * 16 + quad * 4);
        f32x4 e;
#pragma unroll
        for (int rg = 0; rg < 4; ++rg)
          e[rg] = __expf(acc[i][j][rg] + (float)bmv[rg]);
        acc[i][j] = e;
        psum[j] += e[0] + e[1] + e[2] + e[3];
      }
    }
#pragma unroll
    for (int j = 0; j < 4; ++j) {
      float s = psum[j];
      s += __shfl_xor(s, 16);
      s += __shfl_xor(s, 32);
      float inv = (s > 0.f) ? (1.f / s) : 0.f;   // padded queries: sum==0 -> P=0, no NaN
#pragma unroll
      for (int i = 0; i < 4; ++i) {
        bf16x4 pv;
#pragma unroll
        for (int rg = 0; rg < 4; ++rg) pv[rg] = (bf16_t)(acc[i][j][rg] * inv);
        *(bf16x4*)(pw + (j * 16 + l15) * 72 + i * 16 + quad * 4) = pv;
      }
    }

    // O^T[d][n] = sum_m VT[d][m] * P[n][m]
    f32x4 acc2[2][4];
#pragma unroll
    for (int dt = 0; dt < 2; ++dt)
#pragma unroll
      for (int nt = 0; nt < 4; ++nt) {
        f32x4 z = {};
        acc2[dt][nt] = z;
      }
#pragma unroll
    for (int mk = 0; mk < 2; ++mk) {
      bf16x8 vf[2], pf[4];
#pragma unroll
      for (int dt = 0; dt < 2; ++dt)
        vf[dt] = *(const bf16x8*)(vtw + (dt * 16 + l15) * 72 + mk * 32 + quad * 8);
#pragma unroll
      for (int nt = 0; nt < 4; ++nt)
        pf[nt] = *(const bf16x8*)(pw + (nt * 16 + l15) * 72 + mk * 32 + quad * 8);
#pragma unroll
      for (int dt = 0; dt < 2; ++dt)
#pragma unroll
        for (int nt = 0; nt < 4; ++nt)
          acc2[dt][nt] = __builtin_amdgcn_mfma_f32_16x16x32_bf16(vf[dt], pf[nt], acc2[dt][nt], 0, 0, 0);
    }

    // store O[n][d] back over the q slab (this head's Q already consumed)
    bf16_t* O = qr + base;
#pragma unroll
    for (int nt = 0; nt < 4; ++nt) {
      int n = nt * 16 + l15;
      if (n < Nn) {
#pragma unroll
        for (int dt = 0; dt < 2; ++dt) {
          bf16x4 ov;
#pragma unroll
          for (int rg = 0; rg < 4; ++rg) ov[rg] = (bf16_t)acc2[dt][nt][rg];
          *(bf16x4*)(O + n * HD + dt * 16 + quad * 4) = ov;
        }
      }
    }
  }
}

extern "C" void kernel_launch(void* const* d_in, const int* in_sizes, int n_in,
                              void* d_out, int out_size, void* d_ws, size_t ws_size,
                              hipStream_t stream) {
  const float* x      = (const float*)d_in[0];
  const float* qkv_w  = (const float*)d_in[1];
  const float* qkv_b  = (const float*)d_in[2];
  const float* proj_w = (const float*)d_in[3];
  const float* proj_b = (const float*)d_in[4];
  const float* table  = (const float*)d_in[5];
  float* out = (float*)d_out;

  bf16_t* qr = (bf16_t*)d_ws;                 // q, later overwritten with attn_out
  bf16_t* kr = qr + Mtot * Cc;
  bf16_t* vr = kr + Mtot * Cc;
  // bias+mask table lives in d_out (512 KB) — consumed by attn_k, then gemm_k<1>
  // overwrites the whole output buffer afterwards.
  bf16_t* bmb = (bf16_t*)d_out;

  bm_fill<<<dim3(64), dim3(256), 0, stream>>>(table, bmb);
  dim3 g1(784, 12);
  gemm_k<0><<<g1, 256, 0, stream>>>(x, qkv_w, qkv_b, qr, kr, vr, nullptr);
  attn_k<<<dim3(2048), dim3(256), 0, stream>>>(qr, kr, vr, bmb);
  dim3 g3(784, 4);
  gemm_k<1><<<g3, 256, 0, stream>>>(qr, proj_w, proj_b, nullptr, nullptr, nullptr, out);
}

// Round 2
// 806.090 us; speedup vs baseline: 1.4729x; 1.1230x over previous
//
#include <hip/hip_runtime.h>
#include <hip/hip_bf16.h>

typedef __bf16 bf16_t;
typedef __bf16 bf16x8 __attribute__((ext_vector_type(8)));
typedef __bf16 bf16x4 __attribute__((ext_vector_type(4)));
typedef __bf16 bf16x2 __attribute__((ext_vector_type(2)));
typedef float f32x4 __attribute__((ext_vector_type(4)));

typedef const __attribute__((address_space(1))) void* gas_t;
typedef __attribute__((address_space(3))) void* las_t;

constexpr int Hh = 56;
constexpr int Ww = 56;
constexpr int Cc = 512;
constexpr int NHd = 16;
constexpr int HD = 32;
constexpr int SSh = 3;
constexpr int Nn = 49;          // tokens per window
constexpr long Mtot = 100352;   // 32*64*49 windowed tokens
#define SCALE 0.17677669529663687f

// token (windowed order) -> pixel index in x / out. Identical map for gather and scatter.
__device__ __forceinline__ int token_to_pixel(int m) {
  int bw = m / Nn;
  int n  = m - bw * Nn;
  int b  = bw >> 6;
  int w6 = bw & 63;
  int wh = w6 >> 3, ww = w6 & 7;
  int r = n / 7, c = n - r * 7;
  int hh = wh * 7 + r + SSh; if (hh >= Hh) hh -= Hh;
  int wp = ww * 7 + c + SSh; if (wp >= Ww) wp -= Ww;
  return (b * Hh + hh) * Ww + wp;
}

// Gather+convert: x (f32 pixels) -> xb (bf16, windowed token-major), and qkv_w -> bf16.
// One wave per token row (2KB read, 1KB write, fully coalesced).
__global__ __launch_bounds__(256)
void prep_k(const float* __restrict__ x, const float* __restrict__ qkv_w,
            bf16_t* __restrict__ xb, bf16_t* __restrict__ qwb) {
  const int b = blockIdx.x, t = threadIdx.x;
  if (b < (int)(Mtot / 4)) {
    const int m = b * 4 + (t >> 6);
    const int lane = t & 63;
    const float* src = x + (long)token_to_pixel(m) * Cc + lane * 8;
    f32x4 a0 = *(const f32x4*)src;
    f32x4 a1 = *(const f32x4*)(src + 4);
    bf16x8 o;
#pragma unroll
    for (int e = 0; e < 4; ++e) { o[e] = (bf16_t)a0[e]; o[e + 4] = (bf16_t)a1[e]; }
    *(bf16x8*)(xb + (long)m * Cc + lane * 8) = o;
  } else {
    const long off = (long)(b - Mtot / 4) * 2048 + t * 8;
    f32x4 a0 = *(const f32x4*)(qkv_w + off);
    f32x4 a1 = *(const f32x4*)(qkv_w + off + 4);
    bf16x8 o;
#pragma unroll
    for (int e = 0; e < 4; ++e) { o[e] = (bf16_t)a0[e]; o[e + 4] = (bf16_t)a1[e]; }
    *(bf16x8*)(qwb + off) = o;
  }
}

// proj_w f32 -> bf16 (runs after attn_k into the dead kr region)
__global__ __launch_bounds__(256)
void convp_k(const float* __restrict__ w, bf16_t* __restrict__ wb) {
  const long off = (long)blockIdx.x * 2048 + threadIdx.x * 8;
  f32x4 a0 = *(const f32x4*)(w + off);
  f32x4 a1 = *(const f32x4*)(w + off + 4);
  bf16x8 o;
#pragma unroll
  for (int e = 0; e < 4; ++e) { o[e] = (bf16_t)a0[e]; o[e + 4] = (bf16_t)a1[e]; }
  *(bf16x8*)(wb + off) = o;
}

// C[m][n] = sum_k A[m][k]*Wb[n][k] (+bias). Pure bf16 inputs, global_load_lds staging.
// MODE 0: A = xb (token-major), Wb = qkv_wb; scatter bf16 q/k/v into (bw,h,n,d); q pre-scaled.
// MODE 1: A = attn_out in (bw,h,n,d), Wb = proj_wb; scatter f32 to rolled pixel layout.
template <int MODE>
__global__ __launch_bounds__(256, 3)
void gemm_k(const bf16_t* __restrict__ A, const bf16_t* __restrict__ Wb,
            const float* __restrict__ bias,
            bf16_t* __restrict__ oq, bf16_t* __restrict__ okk, bf16_t* __restrict__ ov,
            float* __restrict__ of) {
  __shared__ __align__(16) bf16_t lA[128 * 32];
  __shared__ __align__(16) bf16_t lB[128 * 32];
  const int t = threadIdx.x;
  const int mtile = blockIdx.x, ntile = blockIdx.y;
  const int lane = t & 63;
  const int wave = t >> 6;
  const int wr = wave >> 1, wc = wave & 1;
  const int quad = lane >> 4, l15 = lane & 15;

  // staging: lane covers row = wave*16 + (lane>>2) (+64 for u=1), 16B chunk (lane&3)
  const int rowW = wave * 16 + (lane >> 2);
  const int partE = (lane & 3) * 8;
  const bf16_t* aSrc[2];
  const bf16_t* bSrc[2];
  const long aStep = (MODE == 0) ? 32 : 32 * Nn;  // elements per 32-k slab
#pragma unroll
  for (int u = 0; u < 2; ++u) {
    const int rA = rowW + u * 64;
    const int m = mtile * 128 + rA;
    if (MODE == 0) {
      aSrc[u] = A + (long)m * Cc + partE;
    } else {
      int bw2 = m / Nn, nn = m - bw2 * Nn;
      aSrc[u] = A + (long)bw2 * (NHd * Nn * HD) + nn * HD + partE;
    }
    bSrc[u] = Wb + (long)(ntile * 128 + rA) * Cc + partE;
  }
  // wave-uniform LDS bases: linear layout matches lane*16B exactly
  char* lAb = (char*)lA + wave * 1024;
  char* lBb = (char*)lB + wave * 1024;

  f32x4 acc[4][4] = {};

  for (int it = 0; it < Cc / 32; ++it) {
#pragma unroll
    for (int u = 0; u < 2; ++u) {
      __builtin_amdgcn_global_load_lds((gas_t)aSrc[u], (las_t)(lAb + u * 4096), 16, 0, 0);
      __builtin_amdgcn_global_load_lds((gas_t)bSrc[u], (las_t)(lBb + u * 4096), 16, 0, 0);
      aSrc[u] += aStep;
      bSrc[u] += 32;
    }
    __syncthreads();   // drains vmcnt(0): staged tile visible

    bf16x8 af[4], bfr[4];
#pragma unroll
    for (int i = 0; i < 4; ++i)
      af[i] = *(const bf16x8*)(lA + (wr * 64 + i * 16 + l15) * 32 + quad * 8);
#pragma unroll
    for (int j = 0; j < 4; ++j)
      bfr[j] = *(const bf16x8*)(lB + (wc * 64 + j * 16 + l15) * 32 + quad * 8);
#pragma unroll
    for (int i = 0; i < 4; ++i)
#pragma unroll
      for (int j = 0; j < 4; ++j)
        acc[i][j] = __builtin_amdgcn_mfma_f32_16x16x32_bf16(af[i], bfr[j], acc[i][j], 0, 0, 0);
    __syncthreads();   // fragment reads done before next stage overwrites
  }

#pragma unroll
  for (int i = 0; i < 4; ++i) {
#pragma unroll
    for (int rg = 0; rg < 4; ++rg) {
      int m = mtile * 128 + wr * 64 + i * 16 + quad * 4 + rg;
      if (MODE == 0) {
        int bw = m / Nn, n = m - bw * Nn;
#pragma unroll
        for (int j = 0; j < 4; ++j) {
          int jg = ntile * 128 + wc * 64 + j * 16 + l15;
          float v = acc[i][j][rg] + bias[jg];
          int which = jg >> 9;
          if (which == 0) v *= SCALE;   // fold softmax scale into q
          int h = (jg >> 5) & 15;
          int d = jg & 31;
          long idx = (((long)bw * NHd + h) * Nn + n) * HD + d;
          bf16_t* dst = (which == 0) ? oq : ((which == 1) ? okk : ov);
          dst[idx] = (bf16_t)v;
        }
      } else {
        long pb = (long)token_to_pixel(m) * Cc;
#pragma unroll
        for (int j = 0; j < 4; ++j) {
          int jg = ntile * 128 + wc * 64 + j * 16 + l15;
          of[pb + jg] = acc[i][j][rg] + bias[jg];
        }
      }
    }
  }
}

// Precompute bm[class][h][n][m] = rel-pos bias + shift mask, bf16, [64][64] padded
// with -1e30 for n>=49 or m>=49 (=> exp -> 0, so MFMA padding lanes self-mask).
__global__ void bm_fill(const float* __restrict__ table, bf16_t* __restrict__ bm) {
  const int b = blockIdx.x;           // cls*16 + h
  const int cls = b >> 4, h = b & 15;
  const int whE = cls >> 1, wwE = cls & 1;
  for (int e = threadIdx.x; e < 4096; e += 256) {
    int n = e >> 6, m = e & 63;
    float v = -1e30f;
    if (n < Nn && m < Nn) {
      int r1 = n / 7, c1 = n - r1 * 7;
      int r2 = m / 7, c2 = m - r2 * 7;
      int idx = (r1 - r2 + 6) * 13 + (c1 - c2 + 6);
      v = table[idx * NHd + h];
      int reg1 = (whE ? ((r1 < 4) ? 1 : 2) : 0) * 3 + (wwE ? ((c1 < 4) ? 1 : 2) : 0);
      int reg2 = (whE ? ((r2 < 4) ? 1 : 2) : 0) * 3 + (wwE ? ((c2 < 4) ? 1 : 2) : 0);
      if (reg1 != reg2) v -= 100.f;
    }
    bm[(long)b * 4096 + e] = (bf16_t)v;
  }
}

// MFMA attention. One block per window, 4 waves x 4 heads, no __syncthreads
// (all LDS buffers are per-wave). Per head:
//   S^T = K . Qs^T    (16 mfma, swapped so P is m-contiguous per lane)
//   softmax in-reg    (bm fused bias+mask+pad; 2 shfl_xor row-sum; P -> LDS bf16)
//   O^T = VT . P^T    (16 mfma; output d-contiguous per lane)
// Output overwrites the q region (read-before-write within the wave), layout (bw,h,n,d).
__global__ __launch_bounds__(256, 2)
void attn_k(bf16_t* __restrict__ qr, const bf16_t* __restrict__ kr,
            const bf16_t* __restrict__ vr, const bf16_t* __restrict__ bm) {
  __shared__ __align__(16) bf16_t vt[4][32 * 72];   // V^T per wave: [d][m], stride 72
  __shared__ __align__(16) bf16_t pbuf[4][64 * 72]; // P per wave: [n][m], stride 72
  const int t = threadIdx.x, wave = t >> 6, lane = t & 63;
  const int quad = lane >> 4, l15 = lane & 15;
  const int bw = blockIdx.x;
  const int w6 = bw & 63, wh = w6 >> 3, ww = w6 & 7;
  const int cls = ((wh == 7) ? 2 : 0) | ((ww == 7) ? 1 : 0);
  bf16_t* vtw = vt[wave];
  bf16_t* pw  = pbuf[wave];

  // zero vt once: cols 50..63 stay zero forever (m-padding for PV), avoids NaN garbage
  {
    bf16x8 z = {};
    for (int c = lane; c < 288; c += 64) *(bf16x8*)(vtw + c * 8) = z;
  }

  const int dc = lane & 3;        // d-chunk of 8 for V transpose staging
  const int mp = lane >> 2;       // m-pair index
  const int m2 = 32 + 2 * mp;
  const int ma = (m2 > 48) ? 48 : m2;
  const int mb = (m2 + 1 > 48) ? 48 : m2 + 1;

#pragma unroll 1
  for (int hi = 0; hi < 4; ++hi) {
    const int h = wave * 4 + hi;
    const long base = (long)(bw * NHd + h) * (Nn * HD);
    const bf16_t* K = kr + base;
    const bf16_t* Q = qr + base;
    const bf16_t* V = vr + base;

    // K/Q fragments straight from global: 16 consecutive rows x 64B = coalesced 1KB/instr.
    // Rows 49..63 over-read into the next head slab: finite garbage, masked by bm pad.
    bf16x8 kf[4], qf[4];
#pragma unroll
    for (int i = 0; i < 4; ++i) {
      kf[i] = *(const bf16x8*)(K + (i * 16 + l15) * HD + quad * 8);
      qf[i] = *(const bf16x8*)(Q + (i * 16 + l15) * HD + quad * 8);
    }
    // V staging loads (issued early; LDS transpose-writes happen after the MFMAs)
    bf16x8 v0a = *(const bf16x8*)(V + (2 * mp) * HD + dc * 8);
    bf16x8 v0b = *(const bf16x8*)(V + (2 * mp + 1) * HD + dc * 8);
    bf16x8 v1a = *(const bf16x8*)(V + ma * HD + dc * 8);
    bf16x8 v1b = *(const bf16x8*)(V + mb * HD + dc * 8);

    // S^T[m][n] = sum_d K[m][d] * Qs[n][d]
    f32x4 acc[4][4];
#pragma unroll
    for (int i = 0; i < 4; ++i)
#pragma unroll
      for (int j = 0; j < 4; ++j) {
        f32x4 z = {};
        acc[i][j] = z;
      }
#pragma unroll
    for (int i = 0; i < 4; ++i)
#pragma unroll
      for (int j = 0; j < 4; ++j)
        acc[i][j] = __builtin_amdgcn_mfma_f32_16x16x32_bf16(kf[i], qf[j], acc[i][j], 0, 0, 0);

    // V^T into LDS: vt[d][m], packed bf16x2 writes (pairs of m)
#pragma unroll
    for (int e = 0; e < 8; ++e) {
      int d = dc * 8 + e;
      bf16x2 w0; w0[0] = v0a[e]; w0[1] = v0b[e];
      *(bf16x2*)(vtw + d * 72 + 2 * mp) = w0;
      if (mp <= 8) {
        bf16x2 w1; w1[0] = v1a[e]; w1[1] = (mp < 8) ? v1b[e] : (bf16_t)0.0f;
        *(bf16x2*)(vtw + d * 72 + ma) = w1;
      }
    }

    // bias+mask+pad, exp, row-sum, normalized P -> LDS
    const bf16_t* bmh = bm + ((long)(cls * NHd + h) << 12);
    float psum[4] = {0.f, 0.f, 0.f, 0.f};
#pragma unroll
    for (int j = 0; j < 4; ++j) {
      const int n = j * 16 + l15;
#pragma unroll
      for (int i = 0; i < 4; ++i) {
        bf16x4 bmv = *(const bf16x4*)(bmh + n * 64 + i * 16 + quad * 4);
        f32x4 e;
#pragma unroll
        for (int rg = 0; rg < 4; ++rg)
          e[rg] = __expf(acc[i][j][rg] + (float)bmv[rg]);
        acc[i][j] = e;
        psum[j] += e[0] + e[1] + e[2] + e[3];
      }
    }
#pragma unroll
    for (int j = 0; j < 4; ++j) {
      float s = psum[j];
      s += __shfl_xor(s, 16);
      s += __shfl_xor(s, 32);
      float inv = (s > 0.f) ? (1.f / s) : 0.f;   // padded queries: sum==0 -> P=0, no NaN
#pragma unroll
      for (int i = 0; i < 4; ++i) {
        bf16x4 pv;
#pragma unroll
        for (int rg = 0; rg < 4; ++rg) pv[rg] = (bf16_t)(acc[i][j][rg] * inv);
        *(bf16x4*)(pw + (j * 16 + l15) * 72 + i * 16 + quad * 4) = pv;
      }
    }

    // O^T[d][n] = sum_m VT[d][m] * P[n][m]
    f32x4 acc2[2][4];
#pragma unroll
    for (int dt = 0; dt < 2; ++dt)
#pragma unroll
      for (int nt = 0; nt < 4; ++nt) {
        f32x4 z = {};
        acc2[dt][nt] = z;
      }
#pragma unroll
    for (int mk = 0; mk < 2; ++mk) {
      bf16x8 vf[2], pf[4];
#pragma unroll
      for (int dt = 0; dt < 2; ++dt)
        vf[dt] = *(const bf16x8*)(vtw + (dt * 16 + l15) * 72 + mk * 32 + quad * 8);
#pragma unroll
      for (int nt = 0; nt < 4; ++nt)
        pf[nt] = *(const bf16x8*)(pw + (nt * 16 + l15) * 72 + mk * 32 + quad * 8);
#pragma unroll
      for (int dt = 0; dt < 2; ++dt)
#pragma unroll
        for (int nt = 0; nt < 4; ++nt)
          acc2[dt][nt] = __builtin_amdgcn_mfma_f32_16x16x32_bf16(vf[dt], pf[nt], acc2[dt][nt], 0, 0, 0);
    }

    // store O[n][d] back over the q slab (this head's Q already consumed)
    bf16_t* O = qr + base;
#pragma unroll
    for (int nt = 0; nt < 4; ++nt) {
      int n = nt * 16 + l15;
      if (n < Nn) {
#pragma unroll
        for (int dt = 0; dt < 2; ++dt) {
          bf16x4 ov;
#pragma unroll
          for (int rg = 0; rg < 4; ++rg) ov[rg] = (bf16_t)acc2[dt][nt][rg];
          *(bf16x4*)(O + n * HD + dt * 16 + quad * 4) = ov;
        }
      }
    }
  }
}

extern "C" void kernel_launch(void* const* d_in, const int* in_sizes, int n_in,
                              void* d_out, int out_size, void* d_ws, size_t ws_size,
                              hipStream_t stream) {
  const float* x      = (const float*)d_in[0];
  const float* qkv_w  = (const float*)d_in[1];
  const float* qkv_b  = (const float*)d_in[2];
  const float* proj_w = (const float*)d_in[3];
  const float* proj_b = (const float*)d_in[4];
  const float* table  = (const float*)d_in[5];
  float* out = (float*)d_out;

  bf16_t* qr = (bf16_t*)d_ws;                 // q, later overwritten with attn_out
  bf16_t* kr = qr + Mtot * Cc;
  bf16_t* vr = kr + Mtot * Cc;

  // d_out doubles as scratch for everything consumed before gemm_k<1> runs:
  //   xb  @ 0        : 102,760,448 B (bf16 gathered x)
  //   bm  @ 102.76MB :     524,288 B (bias+mask table)
  //   qwb @ +512KB   :   1,572,864 B (bf16 qkv weights)
  // gemm_k<1> overwrites all of d_out afterwards.
  char* ob = (char*)d_out;
  bf16_t* xb  = (bf16_t*)ob;
  bf16_t* bmb = (bf16_t*)(ob + 102760448);
  bf16_t* qwb = (bf16_t*)(ob + 102760448 + 524288);
  // proj_w bf16 goes into the kr region (dead after attn_k)
  bf16_t* pwb = kr;

  prep_k<<<dim3(Mtot / 4 + 384), dim3(256), 0, stream>>>(x, qkv_w, xb, qwb);
  bm_fill<<<dim3(64), dim3(256), 0, stream>>>(table, bmb);
  dim3 g1(784, 12);
  gemm_k<0><<<g1, 256, 0, stream>>>(xb, qwb, qkv_b, qr, kr, vr, nullptr);
  attn_k<<<dim3(2048), dim3(256), 0, stream>>>(qr, kr, vr, bmb);
  convp_k<<<dim3(128), dim3(256), 0, stream>>>(proj_w, pwb);
  dim3 g3(784, 4);
  gemm_k<1><<<g3, 256, 0, stream>>>(qr, pwb, proj_b, nullptr, nullptr, nullptr, out);
}

// Round 3
// 800.032 us; speedup vs baseline: 1.4841x; 1.0076x over previous
//
#include <hip/hip_runtime.h>
#include <hip/hip_bf16.h>

typedef __bf16 bf16_t;
typedef __bf16 bf16x8 __attribute__((ext_vector_type(8)));
typedef __bf16 bf16x4 __attribute__((ext_vector_type(4)));
typedef __bf16 bf16x2 __attribute__((ext_vector_type(2)));
typedef float f32x4 __attribute__((ext_vector_type(4)));

typedef const __attribute__((address_space(1))) void* gas_t;
typedef __attribute__((address_space(3))) void* las_t;

constexpr int Hh = 56;
constexpr int Ww = 56;
constexpr int Cc = 512;
constexpr int NHd = 16;
constexpr int HD = 32;
constexpr int SSh = 3;
constexpr int Nn = 49;          // tokens per window
constexpr long Mtot = 100352;   // 32*64*49 windowed tokens
#define SCALE 0.17677669529663687f

// token (windowed order) -> pixel index in x / out. Identical map for gather and scatter.
__device__ __forceinline__ int token_to_pixel(int m) {
  int bw = m / Nn;
  int n  = m - bw * Nn;
  int b  = bw >> 6;
  int w6 = bw & 63;
  int wh = w6 >> 3, ww = w6 & 7;
  int r = n / 7, c = n - r * 7;
  int hh = wh * 7 + r + SSh; if (hh >= Hh) hh -= Hh;
  int wp = ww * 7 + c + SSh; if (wp >= Ww) wp -= Ww;
  return (b * Hh + hh) * Ww + wp;
}

// Gather+convert: x (f32 pixels) -> xb (bf16, windowed token-major), and qkv_w -> bf16.
__global__ __launch_bounds__(256)
void prep_k(const float* __restrict__ x, const float* __restrict__ qkv_w,
            bf16_t* __restrict__ xb, bf16_t* __restrict__ qwb) {
  const int b = blockIdx.x, t = threadIdx.x;
  if (b < (int)(Mtot / 4)) {
    const int m = b * 4 + (t >> 6);
    const int lane = t & 63;
    const float* src = x + (long)token_to_pixel(m) * Cc + lane * 8;
    f32x4 a0 = *(const f32x4*)src;
    f32x4 a1 = *(const f32x4*)(src + 4);
    bf16x8 o;
#pragma unroll
    for (int e = 0; e < 4; ++e) { o[e] = (bf16_t)a0[e]; o[e + 4] = (bf16_t)a1[e]; }
    *(bf16x8*)(xb + (long)m * Cc + lane * 8) = o;
  } else {
    const long off = (long)(b - Mtot / 4) * 2048 + t * 8;
    f32x4 a0 = *(const f32x4*)(qkv_w + off);
    f32x4 a1 = *(const f32x4*)(qkv_w + off + 4);
    bf16x8 o;
#pragma unroll
    for (int e = 0; e < 4; ++e) { o[e] = (bf16_t)a0[e]; o[e + 4] = (bf16_t)a1[e]; }
    *(bf16x8*)(qwb + off) = o;
  }
}

// proj_w f32 -> bf16 (into the dead kr region)
__global__ __launch_bounds__(256)
void convp_k(const float* __restrict__ w, bf16_t* __restrict__ wb) {
  const long off = (long)blockIdx.x * 2048 + threadIdx.x * 8;
  f32x4 a0 = *(const f32x4*)(w + off);
  f32x4 a1 = *(const f32x4*)(w + off + 4);
  bf16x8 o;
#pragma unroll
  for (int e = 0; e < 4; ++e) { o[e] = (bf16_t)a0[e]; o[e + 4] = (bf16_t)a1[e]; }
  *(bf16x8*)(wb + off) = o;
}

// C[m][n] = sum_k A[m][k]*Wb[n][k] (+bias). BK=64, XOR-swizzled LDS (rule #21:
// linear global_load_lds dest + inverse-swizzled global SOURCE + swizzled ds_read).
// Grid: blockIdx.x = ntile (fast) so all ntiles of one mtile dispatch adjacently
// -> A-tile read ~once from HBM (L3/L2 serve re-reads), B is L2-resident.
// MODE 0: A = xb (token-major), Wb = qkv_wb; scatter bf16 q/k/v into (bw,h,n,d); q pre-scaled.
// MODE 1: A = attn_out in (bw,h,n,d), Wb = proj_wb; scatter f32 to rolled pixel layout.
template <int MODE>
__global__ __launch_bounds__(256, 3)
void gemm_k(const bf16_t* __restrict__ A, const bf16_t* __restrict__ Wb,
            const float* __restrict__ bias,
            bf16_t* __restrict__ oq, bf16_t* __restrict__ okk, bf16_t* __restrict__ ov,
            float* __restrict__ of) {
  __shared__ __align__(16) bf16_t lA[128 * 64];
  __shared__ __align__(16) bf16_t lB[128 * 64];
  const int t = threadIdx.x;
  const int ntile = blockIdx.x, mtile = blockIdx.y;
  const int lane = t & 63;
  const int wave = t >> 6;
  const int wr = wave >> 1, wc = wave & 1;
  const int quad = lane >> 4, l15 = lane & 15;

  // staging round p: row r = 32p + (t>>3), LDS chunk slot (t&7).
  // Slot (r,c') must hold logical chunk c'^(r&7)  =>  fetch csw = (t&7)^(r&7).
  const int rr = t >> 3;
  const int csw = (t & 7) ^ (rr & 7);
  const bf16_t* aSrc[4];
  const bf16_t* bSrc[4];
  const long aStep = (MODE == 0) ? 64 : (long)2 * Nn * HD;
#pragma unroll
  for (int p = 0; p < 4; ++p) {
    const int r = 32 * p + rr;
    const int m = mtile * 128 + r;
    if (MODE == 0) {
      aSrc[p] = A + (long)m * Cc + csw * 8;
    } else {
      // element (m, k): k = it*64 + csw*8 + e; head = 2*it + (csw>>2), d = (csw&3)*8 + e
      int bw2 = m / Nn, nn = m - bw2 * Nn;
      aSrc[p] = A + (long)bw2 * (NHd * Nn * HD) + (csw >> 2) * (Nn * HD) + nn * HD + (csw & 3) * 8;
    }
    bSrc[p] = Wb + (long)(ntile * 128 + r) * Cc + csw * 8;
  }
  char* lAb = (char*)lA + wave * 1024;
  char* lBb = (char*)lB + wave * 1024;

  const int xsw = l15 & 7;   // row&7 for fragment rows (row = base16*x + l15)
  f32x4 acc[4][4] = {};

  for (int it = 0; it < Cc / 64; ++it) {
#pragma unroll
    for (int p = 0; p < 4; ++p) {
      __builtin_amdgcn_global_load_lds((gas_t)aSrc[p], (las_t)(lAb + p * 4096), 16, 0, 0);
      __builtin_amdgcn_global_load_lds((gas_t)bSrc[p], (las_t)(lBb + p * 4096), 16, 0, 0);
      aSrc[p] += aStep;
      bSrc[p] += 64;
    }
    __syncthreads();   // drains vmcnt(0): staged tile visible
#pragma unroll
    for (int s = 0; s < 2; ++s) {
      bf16x8 af[4], bfr[4];
#pragma unroll
      for (int i = 0; i < 4; ++i)
        af[i] = *(const bf16x8*)(lA + (wr * 64 + i * 16 + l15) * 64 + ((s * 4 + quad) ^ xsw) * 8);
#pragma unroll
      for (int j = 0; j < 4; ++j)
        bfr[j] = *(const bf16x8*)(lB + (wc * 64 + j * 16 + l15) * 64 + ((s * 4 + quad) ^ xsw) * 8);
#pragma unroll
      for (int i = 0; i < 4; ++i)
#pragma unroll
        for (int j = 0; j < 4; ++j)
          acc[i][j] = __builtin_amdgcn_mfma_f32_16x16x32_bf16(af[i], bfr[j], acc[i][j], 0, 0, 0);
    }
    __syncthreads();   // fragment reads done before next stage overwrites
  }

#pragma unroll
  for (int i = 0; i < 4; ++i) {
#pragma unroll
    for (int rg = 0; rg < 4; ++rg) {
      int m = mtile * 128 + wr * 64 + i * 16 + quad * 4 + rg;
      if (MODE == 0) {
        int bw = m / Nn, n = m - bw * Nn;
#pragma unroll
        for (int j = 0; j < 4; ++j) {
          int jg = ntile * 128 + wc * 64 + j * 16 + l15;
          float v = acc[i][j][rg] + bias[jg];
          int which = jg >> 9;
          if (which == 0) v *= SCALE;   // fold softmax scale into q
          int h = (jg >> 5) & 15;
          int d = jg & 31;
          long idx = (((long)bw * NHd + h) * Nn + n) * HD + d;
          bf16_t* dst = (which == 0) ? oq : ((which == 1) ? okk : ov);
          dst[idx] = (bf16_t)v;
        }
      } else {
        long pb = (long)token_to_pixel(m) * Cc;
#pragma unroll
        for (int j = 0; j < 4; ++j) {
          int jg = ntile * 128 + wc * 64 + j * 16 + l15;
          of[pb + jg] = acc[i][j][rg] + bias[jg];
        }
      }
    }
  }
}

// Precompute bm[class][h][n][m] = rel-pos bias + shift mask, bf16, [64][64] padded
// with -1e30 for n>=49 or m>=49 (=> exp -> 0, so MFMA padding lanes self-mask).
__global__ void bm_fill(const float* __restrict__ table, bf16_t* __restrict__ bm) {
  const int b = blockIdx.x;           // cls*16 + h
  const int cls = b >> 4, h = b & 15;
  const int whE = cls >> 1, wwE = cls & 1;
  for (int e = threadIdx.x; e < 4096; e += 256) {
    int n = e >> 6, m = e & 63;
    float v = -1e30f;
    if (n < Nn && m < Nn) {
      int r1 = n / 7, c1 = n - r1 * 7;
      int r2 = m / 7, c2 = m - r2 * 7;
      int idx = (r1 - r2 + 6) * 13 + (c1 - c2 + 6);
      v = table[idx * NHd + h];
      int reg1 = (whE ? ((r1 < 4) ? 1 : 2) : 0) * 3 + (wwE ? ((c1 < 4) ? 1 : 2) : 0);
      int reg2 = (whE ? ((r2 < 4) ? 1 : 2) : 0) * 3 + (wwE ? ((c2 < 4) ? 1 : 2) : 0);
      if (reg1 != reg2) v -= 100.f;
    }
    bm[(long)b * 4096 + e] = (bf16_t)v;
  }
}

// MFMA attention. One block per window, 4 waves x 4 heads serial, no __syncthreads
// (all LDS per-wave; same-wave DS ops are ordered). pbuf is HALF-sized [32][72]:
// P is double-pumped (write j-pair -> read -> overwrite) since acc2[dt][nt] is
// independent per nt. LDS 36.9KB/block -> 4 blocks/CU.
__global__ __launch_bounds__(256, 4)
void attn_k(bf16_t* __restrict__ qr, const bf16_t* __restrict__ kr,
            const bf16_t* __restrict__ vr, const bf16_t* __restrict__ bm) {
  __shared__ __align__(16) bf16_t vt[4][32 * 72];   // V^T per wave: [d][m], stride 72
  __shared__ __align__(16) bf16_t pbuf[4][32 * 72]; // P half-tile per wave: [n%32][m]
  const int t = threadIdx.x, wave = t >> 6, lane = t & 63;
  const int quad = lane >> 4, l15 = lane & 15;
  const int bw = blockIdx.x;
  const int w6 = bw & 63, wh = w6 >> 3, ww = w6 & 7;
  const int cls = ((wh == 7) ? 2 : 0) | ((ww == 7) ? 1 : 0);
  bf16_t* vtw = vt[wave];
  bf16_t* pw  = pbuf[wave];

  // zero vt once: cols 50..63 stay zero forever (m-padding for PV)
  {
    bf16x8 z = {};
    for (int c = lane; c < 288; c += 64) *(bf16x8*)(vtw + c * 8) = z;
  }

  const int dc = lane & 3;        // d-chunk of 8 for V transpose staging
  const int mp = lane >> 2;       // m-pair index
  const int m2 = 32 + 2 * mp;
  const int ma = (m2 > 48) ? 48 : m2;
  const int mb = (m2 + 1 > 48) ? 48 : m2 + 1;

#pragma unroll 1
  for (int hi = 0; hi < 4; ++hi) {
    const int h = wave * 4 + hi;
    const long base = (long)(bw * NHd + h) * (Nn * HD);
    const bf16_t* K = kr + base;
    const bf16_t* Q = qr + base;
    const bf16_t* V = vr + base;

    // K/Q fragments straight from global: 16 consecutive rows x 64B = coalesced 1KB/instr.
    // Rows 49..63 over-read into the next head slab: finite garbage, masked by bm pad.
    bf16x8 kf[4], qf[4];
#pragma unroll
    for (int i = 0; i < 4; ++i) {
      kf[i] = *(const bf16x8*)(K + (i * 16 + l15) * HD + quad * 8);
      qf[i] = *(const bf16x8*)(Q + (i * 16 + l15) * HD + quad * 8);
    }
    // V staging loads (issued early; LDS transpose-writes happen after the MFMAs)
    bf16x8 v0a = *(const bf16x8*)(V + (2 * mp) * HD + dc * 8);
    bf16x8 v0b = *(const bf16x8*)(V + (2 * mp + 1) * HD + dc * 8);
    bf16x8 v1a = *(const bf16x8*)(V + ma * HD + dc * 8);
    bf16x8 v1b = *(const bf16x8*)(V + mb * HD + dc * 8);

    // S^T[m][n] = sum_d K[m][d] * Qs[n][d]
    f32x4 acc[4][4];
#pragma unroll
    for (int i = 0; i < 4; ++i)
#pragma unroll
      for (int j = 0; j < 4; ++j) {
        f32x4 z = {};
        acc[i][j] = z;
      }
#pragma unroll
    for (int i = 0; i < 4; ++i)
#pragma unroll
      for (int j = 0; j < 4; ++j)
        acc[i][j] = __builtin_amdgcn_mfma_f32_16x16x32_bf16(kf[i], qf[j], acc[i][j], 0, 0, 0);

    // V^T into LDS: vt[d][m], packed bf16x2 writes (pairs of m)
#pragma unroll
    for (int e = 0; e < 8; ++e) {
      int d = dc * 8 + e;
      bf16x2 w0; w0[0] = v0a[e]; w0[1] = v0b[e];
      *(bf16x2*)(vtw + d * 72 + 2 * mp) = w0;
      if (mp <= 8) {
        bf16x2 w1; w1[0] = v1a[e]; w1[1] = (mp < 8) ? v1b[e] : (bf16_t)0.0f;
        *(bf16x2*)(vtw + d * 72 + ma) = w1;
      }
    }

    // bias+mask+pad, exp, row-sums
    const bf16_t* bmh = bm + ((long)(cls * NHd + h) << 12);
    float psum[4] = {0.f, 0.f, 0.f, 0.f};
#pragma unroll
    for (int j = 0; j < 4; ++j) {
      const int n = j * 16 + l15;
#pragma unroll
      for (int i = 0; i < 4; ++i) {
        bf16x4 bmv = *(const bf16x4*)(bmh + n * 64 + i * 16 + quad * 4);
        f32x4 e;
#pragma unroll
        for (int rg = 0; rg < 4; ++rg)
          e[rg] = __expf(acc[i][j][rg] + (float)bmv[rg]);
        acc[i][j] = e;
        psum[j] += e[0] + e[1] + e[2] + e[3];
      }
    }
    float inv[4];
#pragma unroll
    for (int j = 0; j < 4; ++j) {
      float s = psum[j];
      s += __shfl_xor(s, 16);
      s += __shfl_xor(s, 32);
      inv[j] = (s > 0.f) ? (1.f / s) : 0.f;   // padded queries: sum==0 -> P=0, no NaN
    }

    // hoist V fragments (vt writes above are same-wave ordered before these reads)
    bf16x8 vf[2][2];
#pragma unroll
    for (int mk = 0; mk < 2; ++mk)
#pragma unroll
      for (int dt = 0; dt < 2; ++dt)
        vf[mk][dt] = *(const bf16x8*)(vtw + (dt * 16 + l15) * 72 + mk * 32 + quad * 8);

    // O^T[d][n] = sum_m VT[d][m] * P[n][m], double-pumped through half-size pbuf
    f32x4 acc2[2][4];
#pragma unroll
    for (int dt = 0; dt < 2; ++dt)
#pragma unroll
      for (int nt = 0; nt < 4; ++nt) {
        f32x4 z = {};
        acc2[dt][nt] = z;
      }
#pragma unroll
    for (int jh = 0; jh < 2; ++jh) {
#pragma unroll
      for (int jl = 0; jl < 2; ++jl) {
        const int j = jh * 2 + jl;
#pragma unroll
        for (int i = 0; i < 4; ++i) {
          bf16x4 pv;
#pragma unroll
          for (int rg = 0; rg < 4; ++rg) pv[rg] = (bf16_t)(acc[i][j][rg] * inv[j]);
          *(bf16x4*)(pw + (jl * 16 + l15) * 72 + i * 16 + quad * 4) = pv;
        }
      }
#pragma unroll
      for (int mk = 0; mk < 2; ++mk) {
        bf16x8 pf[2];
#pragma unroll
        for (int jl = 0; jl < 2; ++jl)
          pf[jl] = *(const bf16x8*)(pw + (jl * 16 + l15) * 72 + mk * 32 + quad * 8);
#pragma unroll
        for (int dt = 0; dt < 2; ++dt)
#pragma unroll
          for (int jl = 0; jl < 2; ++jl)
            acc2[dt][jh * 2 + jl] =
                __builtin_amdgcn_mfma_f32_16x16x32_bf16(vf[mk][dt], pf[jl], acc2[dt][jh * 2 + jl], 0, 0, 0);
      }
    }

    // store O[n][d] back over the q slab (this head's Q already consumed)
    bf16_t* O = qr + base;
#pragma unroll
    for (int nt = 0; nt < 4; ++nt) {
      int n = nt * 16 + l15;
      if (n < Nn) {
#pragma unroll
        for (int dt = 0; dt < 2; ++dt) {
          bf16x4 ov;
#pragma unroll
          for (int rg = 0; rg < 4; ++rg) ov[rg] = (bf16_t)acc2[dt][nt][rg];
          *(bf16x4*)(O + n * HD + dt * 16 + quad * 4) = ov;
        }
      }
    }
  }
}

extern "C" void kernel_launch(void* const* d_in, const int* in_sizes, int n_in,
                              void* d_out, int out_size, void* d_ws, size_t ws_size,
                              hipStream_t stream) {
  const float* x      = (const float*)d_in[0];
  const float* qkv_w  = (const float*)d_in[1];
  const float* qkv_b  = (const float*)d_in[2];
  const float* proj_w = (const float*)d_in[3];
  const float* proj_b = (const float*)d_in[4];
  const float* table  = (const float*)d_in[5];
  float* out = (float*)d_out;

  bf16_t* qr = (bf16_t*)d_ws;                 // q, later overwritten with attn_out
  bf16_t* kr = qr + Mtot * Cc;
  bf16_t* vr = kr + Mtot * Cc;

  // d_out doubles as scratch for everything consumed before gemm_k<1> runs:
  //   xb  @ 0        : 102,760,448 B (bf16 gathered x)
  //   bm  @ 102.76MB :     524,288 B (bias+mask table)
  //   qwb @ +512KB   :   1,572,864 B (bf16 qkv weights)
  char* ob = (char*)d_out;
  bf16_t* xb  = (bf16_t*)ob;
  bf16_t* bmb = (bf16_t*)(ob + 102760448);
  bf16_t* qwb = (bf16_t*)(ob + 102760448 + 524288);
  bf16_t* pwb = kr;   // proj_w bf16 into kr (dead after attn_k)

  prep_k<<<dim3(Mtot / 4 + 384), dim3(256), 0, stream>>>(x, qkv_w, xb, qwb);
  bm_fill<<<dim3(64), dim3(256), 0, stream>>>(table, bmb);
  dim3 g1(12, 784);   // ntile fast -> A-tile reuse across adjacent blocks
  gemm_k<0><<<g1, 256, 0, stream>>>(xb, qwb, qkv_b, qr, kr, vr, nullptr);
  attn_k<<<dim3(2048), dim3(256), 0, stream>>>(qr, kr, vr, bmb);
  convp_k<<<dim3(128), dim3(256), 0, stream>>>(proj_w, pwb);
  dim3 g3(4, 784);
  gemm_k<1><<<g3, 256, 0, stream>>>(qr, pwb, proj_b, nullptr, nullptr, nullptr, out);
}